// Round 1
// baseline (2264.128 us; speedup 1.0000x reference)
//
#include <hip/hip_runtime.h>
#include <math.h>

#define NROWS 32768   // B*T
#define DDIM  512
#define KDIM  2048

#define BM 128
#define BN 128
#define BK 8

// ---------------- row L2 normalize: one wave per row, 4 rows/block ----------
__global__ __launch_bounds__(256) void normalize_rows(
    const float* __restrict__ in, float* __restrict__ out, int nrows)
{
    int wave = threadIdx.x >> 6;
    int lane = threadIdx.x & 63;
    int row  = blockIdx.x * 4 + wave;
    if (row >= nrows) return;
    const float4* src = (const float4*)(in + (size_t)row * DDIM);
    float4* dst = (float4*)(out + (size_t)row * DDIM);
    float4 a = src[lane];
    float4 b = src[lane + 64];
    float ss = a.x*a.x + a.y*a.y + a.z*a.z + a.w*a.w
             + b.x*b.x + b.y*b.y + b.z*b.z + b.w*b.w;
    #pragma unroll
    for (int off = 32; off > 0; off >>= 1) ss += __shfl_down(ss, off, 64);
    ss = __shfl(ss, 0, 64);
    float scale = 1.0f / fmaxf(sqrtf(ss), 1e-6f);
    a.x *= scale; a.y *= scale; a.z *= scale; a.w *= scale;
    b.x *= scale; b.y *= scale; b.z *= scale; b.w *= scale;
    dst[lane] = a;
    dst[lane + 64] = b;
}

__device__ __forceinline__ float gumbel(float u) {
    return -logf(-logf(u + 1e-10f) + 1e-10f);
}

// ---------------- GEMM1: logits = 2*(hf . cb^T) - 2 + g(u) ------------------
// A: hf [N x D] row-major, B: cb_n [K x D] row-major (A*B^T), C: logits [N x K]
__global__ __launch_bounds__(256) void gemm1_logits(
    const float* __restrict__ A, const float* __restrict__ Bm,
    const float* __restrict__ U, float* __restrict__ L)
{
    __shared__ float As[BK][BM];
    __shared__ float Bs[BK][BN];
    int t  = threadIdx.x;
    int tx = t & 15, ty = t >> 4;
    int m0 = blockIdx.y * BM;   // row block (N dim)
    int n0 = blockIdx.x * BN;   // col block (K dim)
    float acc[8][8] = {};

    for (int k0 = 0; k0 < DDIM; k0 += BK) {
        int row = t >> 1, kc = (t & 1) * 4;
        float4 va = *(const float4*)(A  + (size_t)(m0 + row) * DDIM + k0 + kc);
        float4 vb = *(const float4*)(Bm + (size_t)(n0 + row) * DDIM + k0 + kc);
        As[kc+0][row] = va.x; As[kc+1][row] = va.y; As[kc+2][row] = va.z; As[kc+3][row] = va.w;
        Bs[kc+0][row] = vb.x; Bs[kc+1][row] = vb.y; Bs[kc+2][row] = vb.z; Bs[kc+3][row] = vb.w;
        __syncthreads();
        #pragma unroll
        for (int kk = 0; kk < BK; ++kk) {
            float a[8], b[8];
            *(float4*)(a)   = *(float4*)&As[kk][ty*8];
            *(float4*)(a+4) = *(float4*)&As[kk][ty*8+4];
            *(float4*)(b)   = *(float4*)&Bs[kk][tx*8];
            *(float4*)(b+4) = *(float4*)&Bs[kk][tx*8+4];
            #pragma unroll
            for (int i = 0; i < 8; ++i)
                #pragma unroll
                for (int j = 0; j < 8; ++j)
                    acc[i][j] += a[i] * b[j];
        }
        __syncthreads();
    }
    // epilogue: logit = 2*sim - 2 + gumbel(u)
    #pragma unroll
    for (int i = 0; i < 8; ++i) {
        size_t row = (size_t)(m0 + ty*8 + i);
        #pragma unroll
        for (int jj = 0; jj < 2; ++jj) {
            int col = n0 + tx*8 + jj*4;
            float4 u4 = *(const float4*)(U + row * KDIM + col);
            float4 o;
            o.x = 2.0f*acc[i][jj*4+0] - 2.0f + gumbel(u4.x);
            o.y = 2.0f*acc[i][jj*4+1] - 2.0f + gumbel(u4.y);
            o.z = 2.0f*acc[i][jj*4+2] - 2.0f + gumbel(u4.z);
            o.w = 2.0f*acc[i][jj*4+3] - 2.0f + gumbel(u4.w);
            *(float4*)(L + row * KDIM + col) = o;
        }
    }
}

// ---------------- softmax + argmax per row (in-place logits -> q) -----------
__global__ __launch_bounds__(256) void softmax_rows(
    float* __restrict__ L, float* __restrict__ out_idx_f, int* __restrict__ ws_idx)
{
    int row = blockIdx.x;
    int t = threadIdx.x;
    float* lr = L + (size_t)row * KDIM;
    float v[8];
    float lmax = -INFINITY; int limax = 0;
    #pragma unroll
    for (int j = 0; j < 8; ++j) {
        int c = t + 256 * j;
        v[j] = lr[c];
        if (v[j] > lmax) { lmax = v[j]; limax = c; }
    }
    __shared__ float smax[256];
    __shared__ int   sidx[256];
    __shared__ float ssum[256];
    smax[t] = lmax; sidx[t] = limax;
    __syncthreads();
    for (int s = 128; s > 0; s >>= 1) {
        if (t < s) {
            float o = smax[t+s]; int oi = sidx[t+s];
            if (o > smax[t] || (o == smax[t] && oi < sidx[t])) { smax[t] = o; sidx[t] = oi; }
        }
        __syncthreads();
    }
    float m = smax[0];
    float lsum = 0.0f;
    #pragma unroll
    for (int j = 0; j < 8; ++j) { v[j] = expf(v[j] - m); lsum += v[j]; }
    ssum[t] = lsum;
    __syncthreads();
    for (int s = 128; s > 0; s >>= 1) {
        if (t < s) ssum[t] += ssum[t+s];
        __syncthreads();
    }
    float inv = 1.0f / ssum[0];
    #pragma unroll
    for (int j = 0; j < 8; ++j) lr[t + 256*j] = v[j] * inv;
    if (t == 0) { out_idx_f[row] = (float)sidx[0]; ws_idx[row] = sidx[0]; }
}

// ---------------- GEMM2: c_tilde = q . cb  (A[NxK] * B[KxD]) ----------------
__global__ __launch_bounds__(256) void gemm2_ctilde(
    const float* __restrict__ Q, const float* __restrict__ Cb, float* __restrict__ Ct)
{
    __shared__ float As[BK][BM];
    __shared__ float Bs[BK][BN];   // Bs[k][d]
    int t  = threadIdx.x;
    int tx = t & 15, ty = t >> 4;
    int m0 = blockIdx.y * BM;   // N dim
    int n0 = blockIdx.x * BN;   // D dim (gridDim.x = 4)
    float acc[8][8] = {};

    for (int k0 = 0; k0 < KDIM; k0 += BK) {
        int row = t >> 1, kc = (t & 1) * 4;
        float4 va = *(const float4*)(Q + (size_t)(m0 + row) * KDIM + k0 + kc);
        As[kc+0][row] = va.x; As[kc+1][row] = va.y; As[kc+2][row] = va.z; As[kc+3][row] = va.w;
        int krow = t >> 5, dc = (t & 31) * 4;
        *(float4*)&Bs[krow][dc] = *(const float4*)(Cb + (size_t)(k0 + krow) * DDIM + n0 + dc);
        __syncthreads();
        #pragma unroll
        for (int kk = 0; kk < BK; ++kk) {
            float a[8], b[8];
            *(float4*)(a)   = *(float4*)&As[kk][ty*8];
            *(float4*)(a+4) = *(float4*)&As[kk][ty*8+4];
            *(float4*)(b)   = *(float4*)&Bs[kk][tx*8];
            *(float4*)(b+4) = *(float4*)&Bs[kk][tx*8+4];
            #pragma unroll
            for (int i = 0; i < 8; ++i)
                #pragma unroll
                for (int j = 0; j < 8; ++j)
                    acc[i][j] += a[i] * b[j];
        }
        __syncthreads();
    }
    #pragma unroll
    for (int i = 0; i < 8; ++i) {
        size_t row = (size_t)(m0 + ty*8 + i);
        #pragma unroll
        for (int jj = 0; jj < 2; ++jj) {
            int col = n0 + tx*8 + jj*4;
            *(float4*)(Ct + row * DDIM + col) = *(float4*)&acc[i][jj*4];
        }
    }
}

// ---------------- gather c_hard/c_quant + per-row squared-diff partials -----
__global__ __launch_bounds__(256) void gather_loss(
    const float* __restrict__ Cb, const int* __restrict__ ws_idx,
    const float* __restrict__ Ct, const float* __restrict__ Hf,
    float* __restrict__ c_hard, float* __restrict__ c_quant,
    float* __restrict__ partials)
{
    int row = blockIdx.x, t = threadIdx.x;
    int idx = ws_idx[row];
    float2 cv = ((const float2*)(Cb + (size_t)idx * DDIM))[t];
    ((float2*)(c_hard  + (size_t)row * DDIM))[t] = cv;
    ((float2*)(c_quant + (size_t)row * DDIM))[t] = cv;
    float2 ct = ((const float2*)(Ct + (size_t)row * DDIM))[t];
    float2 hf = ((const float2*)(Hf + (size_t)row * DDIM))[t];
    float dx = ct.x - hf.x, dy = ct.y - hf.y;
    __shared__ float red[256];
    red[t] = dx*dx + dy*dy;
    __syncthreads();
    for (int s = 128; s > 0; s >>= 1) {
        if (t < s) red[t] += red[t+s];
        __syncthreads();
    }
    if (t == 0) partials[row] = red[0];
}

__global__ __launch_bounds__(1024) void loss_reduce(
    const float* __restrict__ partials, float* __restrict__ loss_out)
{
    int t = threadIdx.x;
    float s = 0.0f;
    for (int i = t; i < NROWS; i += 1024) s += partials[i];
    __shared__ float red[1024];
    red[t] = s;
    __syncthreads();
    for (int st = 512; st > 0; st >>= 1) {
        if (t < st) red[t] += red[t+st];
        __syncthreads();
    }
    if (t == 0) loss_out[0] = red[0] * (1.25f / ((float)NROWS * (float)DDIM));
}

extern "C" void kernel_launch(void* const* d_in, const int* in_sizes, int n_in,
                              void* d_out, int out_size, void* d_ws, size_t ws_size,
                              hipStream_t stream) {
    const float* h  = (const float*)d_in[0];
    const float* cb = (const float*)d_in[1];
    const float* u  = (const float*)d_in[2];

    float* out     = (float*)d_out;
    float* q       = out;                                   // N*K
    float* c_tilde = out + (size_t)NROWS * KDIM;            // N*D
    float* c_hard  = c_tilde + (size_t)NROWS * DDIM;
    float* c_quant = c_hard  + (size_t)NROWS * DDIM;
    float* loss    = c_quant + (size_t)NROWS * DDIM;        // 1
    float* idx_f   = loss + 1;                              // N

    float* hf   = (float*)d_ws;                             // N*D
    float* cb_n = hf + (size_t)NROWS * DDIM;                // K*D
    int*   ws_idx   = (int*)(cb_n + (size_t)KDIM * DDIM);   // N ints
    float* partials = (float*)(ws_idx + NROWS);             // N floats

    normalize_rows<<<KDIM / 4, 256, 0, stream>>>(cb, cb_n, KDIM);
    normalize_rows<<<NROWS / 4, 256, 0, stream>>>(h, hf, NROWS);

    dim3 g1(KDIM / BN, NROWS / BM);
    gemm1_logits<<<g1, 256, 0, stream>>>(hf, cb_n, u, q);

    softmax_rows<<<NROWS, 256, 0, stream>>>(q, idx_f, ws_idx);

    dim3 g2(DDIM / BN, NROWS / BM);
    gemm2_ctilde<<<g2, 256, 0, stream>>>(q, cb_n, c_tilde);

    gather_loss<<<NROWS, 256, 0, stream>>>(cb_n, ws_idx, c_tilde, hf, c_hard, c_quant, partials);
    loss_reduce<<<1, 1024, 0, stream>>>(partials, loss);
}